// Round 9
// baseline (3623499.609 us; speedup 1.0000x reference)
//
#include <hip/hip_runtime.h>
#include <cstdint>
#include <cstddef>

#define B_ 64
#define T_ 512
#define D_ 300
#define DP_ 320
#define H_ 256
#define G4_ 1024
#define NL_ 6

typedef float f32x4 __attribute__((ext_vector_type(4)));
typedef __bf16 bf16x8 __attribute__((ext_vector_type(8)));

struct WPtrs { const float* W[NL_]; const float* Bv[NL_]; };

__device__ __forceinline__ unsigned short f2bf(float f){
  unsigned int u = __float_as_uint(f);
  unsigned int r = u + 0x7FFFu + ((u >> 16) & 1u);
  return (unsigned short)(r >> 16);
}
__device__ __forceinline__ float bf2f(unsigned int s){
  return __uint_as_float((s & 0xFFFFu) << 16);
}
__device__ __forceinline__ float fast_sig(float x){
  return __builtin_amdgcn_rcpf(1.f + __builtin_amdgcn_exp2f(-1.4426950408889634f * x));
}
__device__ __forceinline__ float fast_tanh(float x){
  return 1.f - 2.f * __builtin_amdgcn_rcpf(1.f + __builtin_amdgcn_exp2f(2.8853900817779268f * x));
}
__device__ __forceinline__ void store8bf(unsigned short* p, const unsigned short v[8]){
  uint4 u;
  u.x = (unsigned)v[0] | ((unsigned)v[1] << 16);
  u.y = (unsigned)v[2] | ((unsigned)v[3] << 16);
  u.z = (unsigned)v[4] | ((unsigned)v[5] << 16);
  u.w = (unsigned)v[6] | ((unsigned)v[7] << 16);
  *(uint4*)p = u;
}

// ---------- Phase 0a: x -> bf16 A-frag layout xf[dir][t][bt4][kt10][lane64][e8] ----------
__global__ void k_prep_x(const float* __restrict__ x, const int* __restrict__ len,
                         unsigned short* __restrict__ xf){
  int idx = blockIdx.x * 256 + threadIdx.x;    // over 2*512*4*10*64 = 2,621,440
  int lane = idx & 63;
  int kt = (idx >> 6) % 10;
  int r1 = idx / 640;
  int bt = r1 & 3;
  int r2 = r1 >> 2;
  int t = r2 & 511;
  int dir = r2 >> 9;
  if (dir >= 2) return;
  int bb = bt * 16 + (lane & 15);
  int k0 = kt * 32 + (lane >> 4) * 8;
  int L = len[bb];
  int tsrc = dir ? ((t < L) ? (L - 1 - t) : t) : t;
  const float* xs = x + ((size_t)bb * T_ + tsrc) * D_;
  unsigned short v[8];
  #pragma unroll
  for (int e = 0; e < 8; e++){
    int k = k0 + e;
    v[e] = f2bf(k < D_ ? xs[k] : 0.f);
  }
  store8bf(xf + ((size_t)idx) * 8, v);
}

// ---------- Phase 0b: prepack weights (frag indexing HW-verified rounds 2-6) ----------
__global__ void k_prep_w(WPtrs wp, unsigned short* __restrict__ whp,
                         unsigned short* __restrict__ wxp,
                         const float* __restrict__ W1, const float* __restrict__ W2,
                         float* __restrict__ w1t, float* __restrict__ w2t){
  int idx = blockIdx.x * 256 + threadIdx.x;
  const int nWh = NL_ * 16 * 4 * 8 * 64;   // 196608
  const int nWx = NL_ * 16 * 10 * 4 * 64;  // 245760
  if (idx < nWh){
    int lane = idx & 63, kt = (idx >> 6) & 7, g = (idx >> 9) & 3, s = (idx >> 11) & 15, l = idx >> 15;
    int col = g * 256 + s * 16 + (lane & 15);
    int k0 = kt * 32 + (lane >> 4) * 8;
    const float* W = wp.W[l];
    unsigned short v[8];
    #pragma unroll
    for (int e = 0; e < 8; e++) v[e] = f2bf(W[(size_t)(D_ + k0 + e) * G4_ + col]);
    store8bf(whp + ((((size_t)(l * 16 + s) * 4 + g) * 8 + kt) * 64 + lane) * 8, v);
  } else if (idx < nWh + nWx){
    int i2 = idx - nWh;
    int lane = i2 & 63;
    int g = (i2 >> 6) & 3;
    int r = i2 >> 8;
    int kt = r % 10;
    int r2 = r / 10;
    int s = r2 & 15, l = r2 >> 4;
    int col = g * 256 + s * 16 + (lane & 15);
    int k0 = kt * 32 + (lane >> 4) * 8;
    const float* W = wp.W[l];
    unsigned short v[8];
    #pragma unroll
    for (int e = 0; e < 8; e++){
      int k = k0 + e;
      v[e] = f2bf(k < D_ ? W[(size_t)k * G4_ + col] : 0.f);
    }
    store8bf(wxp + ((((size_t)(l * 16 + s) * 10 + kt) * 4 + g) * 64 + lane) * 8, v);
  } else if (idx < nWh + nWx + 16384){
    int i2 = idx - nWh - nWx;
    int h = i2 & 1023, k = i2 >> 10;
    w1t[k * G4_ + h] = (k < 10) ? W1[h * 10 + k] : 0.f;
  } else if (idx < nWh + nWx + 32768){
    int i2 = idx - nWh - nWx - 16384;
    int h = i2 & 1023, k = i2 >> 10;
    w2t[k * G4_ + h] = (k < 12) ? W2[h * 12 + k] : 0.f;
  }
}

// hpub region (per l, slot, wave): 2048 u64 = 16 rows x 256 units as tagged u32 pairs,
// consumer-frag ordered (HW-verified r5/r6). XCD-local: plain stores -> local L2;
// sc0 loads bypass L1 and are served by the same L2.
#define LOADH_SC0() \
  { _Pragma("unroll") \
    for (int g2i = 0; g2i < 4; g2i++){ \
      const unsigned long long* bp = hbase + (size_t)g2i * 512; \
      _Pragma("unroll") \
      for (int j2 = 0; j2 < 8; j2++){ \
        asm volatile("global_load_dwordx2 %0, %1, off offset:%2 sc0" \
                     : "=v"(hq[g2i * 2 + (j2 >> 2)][j2 & 3]) \
                     : "v"(bp), "i"(j2 * 512)); \
      } \
    } \
    asm volatile("s_waitcnt vmcnt(0)" ::: "memory"); \
    __builtin_amdgcn_sched_barrier(0); \
  }

// cheap tag-only check (3 VALU/u64)
#define CHECKH() \
  { accor = 0u; \
    _Pragma("unroll") \
    for (int kt = 0; kt < 8; kt++) \
      _Pragma("unroll") \
      for (int jj = 0; jj < 4; jj++){ \
        unsigned lo = (unsigned)hq[kt][jj]; \
        unsigned hi = (unsigned)(hq[kt][jj] >> 32); \
        accor |= __builtin_amdgcn_perm(hi, lo, 0x07060302u) ^ cmpw; \
      } }

// data unpack once valid (1 perm/u64)
#define UNPACK_DATA() \
  { _Pragma("unroll") \
    for (int kt = 0; kt < 8; kt++){ \
      union { unsigned u[4]; bf16x8 v; } uu; \
      _Pragma("unroll") \
      for (int jj = 0; jj < 4; jj++){ \
        unsigned lo = (unsigned)hq[kt][jj]; \
        unsigned hi = (unsigned)(hq[kt][jj] >> 32); \
        uu.u[jj] = __builtin_amdgcn_perm(hi, lo, 0x05040100u); \
      } \
      Ah[kt] = uu.v; \
    } }

// One LSTM step, round-6 ordering: xMFMA -> h-load(t-1)+hot-spin -> hMFMA -> gates ->
// publish -> ho. PC holds xf[t] (prefetched last step); PF gets xf[t+1].
#define STEP(TT, PC, PF) do { \
    if ((TT) + 1 < T_){ \
      _Pragma("unroll") \
      for (int kt = 0; kt < 10; kt++) \
        PF[kt] = *(const bf16x8*)(xw + (size_t)((TT) + 1) * 20480 + kt * 512); \
    } \
    f32x4 acc[4]; \
    _Pragma("unroll") \
    for (int g = 0; g < 4; g++){ acc[g].x = 0.f; acc[g].y = 0.f; acc[g].z = 0.f; acc[g].w = 0.f; } \
    _Pragma("unroll") \
    for (int kt = 0; kt < 10; kt++){ \
      _Pragma("unroll") \
      for (int g = 0; g < 4; g++){ \
        bf16x8 Bxf = *(const bf16x8*)(bxs + ((size_t)(kt * 4 + g) * 64) * 8); \
        acc[g] = __builtin_amdgcn_mfma_f32_16x16x32_bf16(PC[kt], Bxf, acc[g], 0, 0, 0); \
      } \
    } \
    if ((TT) > 0){ \
      const unsigned long long* hbase = \
          hpub + (((size_t)(l * 2 + (((TT) - 1) & 1)) * 4 + w) * 2048) + lane; \
      unsigned long long hq[8][4]; \
      bf16x8 Ah[8]; \
      unsigned accor; \
      const unsigned cmpw = ((unsigned)((TT) - 1)) * 0x00010001u; \
      LOADH_SC0(); \
      CHECKH(); \
      int tries = 0; \
      while (__any(accor != 0) && ++tries < 16384){ \
        LOADH_SC0(); \
        CHECKH(); \
      } \
      UNPACK_DATA(); \
      _Pragma("unroll") \
      for (int kt = 0; kt < 8; kt++) \
        _Pragma("unroll") \
        for (int g = 0; g < 4; g++) \
          acc[g] = __builtin_amdgcn_mfma_f32_16x16x32_bf16(Ah[kt], Bh[g][kt], acc[g], 0, 0, 0); \
    } \
    unsigned short hpb[4], hov[4]; \
    _Pragma("unroll") \
    for (int r = 0; r < 4; r++){ \
      float gi = acc[0][r] + bias[0], gj = acc[1][r] + bias[1]; \
      float gf = acc[2][r] + bias[2], go = acc[3][r] + bias[3]; \
      float cn = fast_sig(gf + 1.f) * c4[r] + fast_sig(gi) * fast_tanh(gj); \
      float hn = fast_sig(go) * fast_tanh(cn); \
      bool m = ((TT) < Lr[r]); \
      c4[r] = m ? cn : c4[r]; \
      h4[r] = m ? hn : h4[r]; \
      hpb[r] = f2bf(h4[r]); \
      hov[r] = f2bf(m ? hn : 0.f); \
    } \
    unsigned tagt = ((unsigned)(TT)) << 16; \
    _Pragma("unroll") \
    for (int rr = 0; rr < 4; rr++) \
      lds_pub[lbase + (g2 * 4 + rr) * 2] = tagt | (unsigned)hpb[rr]; \
    { unsigned long long* hrego = hpub + (((size_t)(l * 2 + ((TT) & 1)) * 4 + w) * 2048); \
      hrego[so0]      = lds64[rb0]; \
      hrego[so0 + 16] = lds64[rb1]; } \
    _Pragma("unroll") \
    for (int rr = 0; rr < 4; rr++){ \
      int bb2 = w * 16 + (lane >> 4) * 4 + rr; \
      int tdst = dir ? (((TT) < Lr[rr]) ? (Lr[rr] - 1 - (TT)) : (TT)) : (TT); \
      ho[(((size_t)l * B_ + bb2) * T_ + tdst) * H_ + unit] = hov[rr]; \
    } \
  } while (0)

// ---------- Phase 1: fused recurrent LSTM; round-6 structure + hot spin + xf reg-prefetch ----------
__global__ __launch_bounds__(256, 1) void k_rec(
    const unsigned short* __restrict__ whp, const unsigned short* __restrict__ wxp,
    const unsigned short* __restrict__ xf, WPtrs wp, const int* __restrict__ len,
    unsigned long long* __restrict__ hpub, unsigned short* __restrict__ ho,
    int* __restrict__ pool){
  __shared__ int role_sh;
  int xcc;
  asm volatile("s_getreg_b32 %0, hwreg(HW_REG_XCC_ID)" : "=s"(xcc));
  if (threadIdx.x == 0){
    int r = atomicAdd(&pool[xcc & 7], 1);      // device-scope, once per wg
    role_sh = (xcc < NL_ && r < 16) ? r : -1;
  }
  __syncthreads();
  int s = role_sh;
  if (s < 0) return;
  int l = xcc;                                  // LSTM l lives entirely on XCD l
  int tid = threadIdx.x, lane = tid & 63, w = tid >> 6;
  const int dir = l & 1;

  __shared__ unsigned int lds_pub[1024];   // wave-private redistribute

  // resident Wh B-frags [gate][kt] (128 VGPRs)
  bf16x8 Bh[4][8];
  #pragma unroll
  for (int g = 0; g < 4; g++)
    #pragma unroll
    for (int kt = 0; kt < 8; kt++)
      Bh[g][kt] = *(const bf16x8*)(whp + ((((size_t)(l * 16 + s) * 4 + g) * 8 + kt) * 64 + lane) * 8);
  // Wx streamed from L2 each step (matches round-6 compiler behavior; frees 160 VGPRs)
  const unsigned short* bxs = wxp + (size_t)(l * 16 + s) * 10 * 4 * 64 * 8 + (size_t)lane * 8;

  float bias[4];
  #pragma unroll
  for (int g = 0; g < 4; g++) bias[g] = wp.Bv[l][g * 256 + s * 16 + (lane & 15)];

  float c4[4] = {0.f, 0.f, 0.f, 0.f};
  float h4[4] = {0.f, 0.f, 0.f, 0.f};
  int Lr[4];
  #pragma unroll
  for (int r = 0; r < 4; r++) Lr[r] = len[w * 16 + (lane >> 4) * 4 + r];

  int unit = s * 16 + (lane & 15);
  const int kt_s = s >> 1, qc0 = (s & 1) * 2;
  const int rp = lane & 15, g2 = lane >> 4;
  const int pjj = (rp >> 1) & 3, pqh = rp >> 3, ppp = rp & 1;
  const int lbase = w * 256 + (pjj * 2 + pqh) * 32 + ppp;
  unsigned long long* lds64 = (unsigned long long*)lds_pub;
  const int rb0 = w * 128 + ((lane >> 4) * 2 + 0) * 16 + (lane & 15);
  const int rb1 = rb0 + 16;
  const size_t so0 = (size_t)(kt_s * 4 + (lane >> 4)) * 64 + qc0 * 16 + (lane & 15);

  // xf per-wave base; element (t,kt): xw + t*20480 + kt*512 (shorts) — verified r2-r6 layout
  const unsigned short* xw = xf + ((size_t)(dir * T_) * 4 + w) * 5120 + lane * 8;

  // prologue: P0 <- xf[0]
  bf16x8 P0[10], P1[10];
  #pragma unroll
  for (int kt = 0; kt < 10; kt++)
    P0[kt] = *(const bf16x8*)(xw + kt * 512);

  #pragma unroll 1
  for (int t2 = 0; t2 < T_; t2 += 2){
    STEP(t2,     P0, P1);
    STEP(t2 + 1, P1, P0);
  }
}

// ---------- Phase 3: logits = concat(ho) @ W + b  (wave per (b,t)) ----------
__global__ void k_logits(const unsigned short* __restrict__ ho,
                         const float* __restrict__ w1t, const float* __restrict__ w2t,
                         const float* __restrict__ b1, const float* __restrict__ b2,
                         float* __restrict__ lgt){
  int gid = blockIdx.x * 4 + (threadIdx.x >> 6);   // 0..32767 = b*512+t
  int lane = threadIdx.x & 63;
  int b = gid >> 9, t = gid & 511;
  float hv[6][4];
  #pragma unroll
  for (int lgi = 0; lgi < 6; lgi++){
    const unsigned short* hrow = ho + (((size_t)lgi * B_ + b) * T_ + t) * H_;
    uint2 u = *(const uint2*)(hrow + lane * 4);
    hv[lgi][0] = bf2f(u.x); hv[lgi][1] = bf2f(u.x >> 16);
    hv[lgi][2] = bf2f(u.y); hv[lgi][3] = bf2f(u.y >> 16);
  }
  float s1[10], s2[12];
  #pragma unroll
  for (int k = 0; k < 10; k++) s1[k] = 0.f;
  #pragma unroll
  for (int k = 0; k < 12; k++) s2[k] = 0.f;
  const int seg1[4] = {0, 1, 4, 5};
  const int seg2[4] = {2, 3, 4, 5};
  #pragma unroll
  for (int k = 0; k < 10; k++){
    #pragma unroll
    for (int ii = 0; ii < 4; ii++){
      float4 wv = *(const float4*)(w1t + k * G4_ + ii * 256 + lane * 4);
      int lgi = seg1[ii];
      s1[k] += hv[lgi][0] * wv.x + hv[lgi][1] * wv.y + hv[lgi][2] * wv.z + hv[lgi][3] * wv.w;
    }
  }
  #pragma unroll
  for (int k = 0; k < 12; k++){
    #pragma unroll
    for (int ii = 0; ii < 4; ii++){
      float4 wv = *(const float4*)(w2t + k * G4_ + ii * 256 + lane * 4);
      int lgi = seg2[ii];
      s2[k] += hv[lgi][0] * wv.x + hv[lgi][1] * wv.y + hv[lgi][2] * wv.z + hv[lgi][3] * wv.w;
    }
  }
  #pragma unroll
  for (int k = 0; k < 10; k++)
    #pragma unroll
    for (int d = 1; d < 64; d <<= 1) s1[k] += __shfl_xor(s1[k], d, 64);
  #pragma unroll
  for (int k = 0; k < 12; k++)
    #pragma unroll
    for (int d = 1; d < 64; d <<= 1) s2[k] += __shfl_xor(s2[k], d, 64);
  if (lane == 0){
    float* o1 = lgt + ((size_t)(0 * B_ + b) * T_ + t) * 16;
    float* o2 = lgt + ((size_t)(1 * B_ + b) * T_ + t) * 16;
    #pragma unroll
    for (int k = 0; k < 10; k++) o1[k] = s1[k] + b1[k];
    #pragma unroll
    for (int k = 0; k < 12; k++) o2[k] = s2[k] + b2[k];
  }
}

// ---------- Phase 4: CRF NLL (wave per (task, b)) ----------
__global__ void k_crf(const float* __restrict__ lgt, const int* __restrict__ labels,
                      const int* __restrict__ len, const float* __restrict__ trans1,
                      const float* __restrict__ trans2, float* __restrict__ out){
  int gid = blockIdx.x * 4 + (threadIdx.x >> 6);    // 0..127
  int lane = threadIdx.x & 63;
  int tau = gid >> 6;
  int b = gid & 63;
  int K = tau ? 12 : 10;
  const float* tr = tau ? trans2 : trans1;
  const float* lgp = lgt + (size_t)(tau * B_ + b) * T_ * 16;
  int L = len[b];
  int k2 = lane & 15;
  const float LOG2E = 1.4426950408889634f;
  const float LN2 = 0.6931471805599453f;
  float Et[12];
  #pragma unroll
  for (int k1 = 0; k1 < 12; k1++)
    Et[k1] = (k1 < K && k2 < K) ? __builtin_amdgcn_exp2f(LOG2E * tr[k1 * K + k2]) : 0.f;
  float alpha = (k2 < K) ? lgp[k2] : -1e30f;
  for (int t = 1; t < L; t++){
    float m = alpha;
    #pragma unroll
    for (int d = 1; d < 16; d <<= 1) m = fmaxf(m, __shfl_xor(m, d, 16));
    float e = __builtin_amdgcn_exp2f(LOG2E * (alpha - m));
    float ss = 0.f;
    #pragma unroll
    for (int k1 = 0; k1 < 12; k1++)
      ss += __shfl(e, k1, 16) * Et[k1];
    float na = m + LN2 * __builtin_amdgcn_logf(ss) + lgp[t * 16 + k2];
    alpha = (k2 < K) ? na : -1e30f;
  }
  float m2 = alpha;
  #pragma unroll
  for (int d = 1; d < 16; d <<= 1) m2 = fmaxf(m2, __shfl_xor(m2, d, 16));
  float e2 = __builtin_amdgcn_exp2f(LOG2E * (alpha - m2));
  #pragma unroll
  for (int d = 1; d < 16; d <<= 1) e2 += __shfl_xor(e2, d, 16);
  float logZ = m2 + LN2 * __builtin_amdgcn_logf(e2);
  float us = 0.f;
  const int* lab = labels + b * T_;
  for (int t0 = lane; t0 < L; t0 += 64){
    int la = lab[t0];
    us += lgp[t0 * 16 + la];
    if (t0 >= 1) us += tr[lab[t0 - 1] * K + la];
  }
  #pragma unroll
  for (int d = 1; d < 64; d <<= 1) us += __shfl_xor(us, d, 64);
  if (lane == 0) out[tau * B_ + b] = logZ - us;
}

extern "C" void kernel_launch(void* const* d_in, const int* in_sizes, int n_in,
                              void* d_out, int out_size, void* d_ws, size_t ws_size,
                              hipStream_t stream){
  const float* x = (const float*)d_in[0];
  const int* len = (const int*)d_in[1];
  const int* labels = (const int*)d_in[2];
  WPtrs wp;
  for (int l = 0; l < NL_; l++){
    wp.W[l] = (const float*)d_in[3 + 2 * l];
    wp.Bv[l] = (const float*)d_in[4 + 2 * l];
  }
  const float* W1 = (const float*)d_in[15];
  const float* b1 = (const float*)d_in[16];
  const float* W2 = (const float*)d_in[17];
  const float* b2 = (const float*)d_in[18];
  const float* trans1 = (const float*)d_in[19];
  const float* trans2 = (const float*)d_in[20];

  char* ws = (char*)d_ws;
  const size_t SZ_HPUB = (size_t)NL_ * 2 * 4 * 2048 * 8;      //   786,432
  const size_t O_WHP = SZ_HPUB;
  const size_t SZ_WHP = (size_t)NL_ * H_ * G4_ * 2;           // 3,145,728
  const size_t O_WXP = O_WHP + SZ_WHP;
  const size_t SZ_WXP = (size_t)NL_ * DP_ * G4_ * 2;          // 3,932,160
  const size_t O_XF  = O_WXP + SZ_WXP;
  const size_t SZ_XF = 2ull * T_ * 4 * 10 * 64 * 8 * 2;       // 41,943,040
  const size_t O_HO  = O_XF + SZ_XF;
  const size_t SZ_HO = (size_t)NL_ * B_ * T_ * H_ * 2;        // 100,663,296
  const size_t O_LGT = O_HO + SZ_HO;
  const size_t SZ_LGT = 2ull * B_ * T_ * 16 * 4;              //   8,388,608
  const size_t O_W1T = O_LGT + SZ_LGT;
  const size_t O_W2T = O_W1T + 65536;
  const size_t O_POOL = O_W2T + 65536;                        // 8 ints (per-XCD claim pool)

  unsigned long long* hpub = (unsigned long long*)(ws + 0);
  unsigned short* whp = (unsigned short*)(ws + O_WHP);
  unsigned short* wxp = (unsigned short*)(ws + O_WXP);
  unsigned short* xf  = (unsigned short*)(ws + O_XF);
  unsigned short* ho  = (unsigned short*)(ws + O_HO);
  float* lgt = (float*)(ws + O_LGT);
  float* w1t = (float*)(ws + O_W1T);
  float* w2t = (float*)(ws + O_W2T);
  int* pool = (int*)(ws + O_POOL);

  // invalidate all tags (0xFFFF != any t in [0,512)) + zero the claim pool — replay safety
  hipMemsetAsync(hpub, 0xFF, SZ_HPUB, stream);
  hipMemsetAsync(pool, 0, 64, stream);
  k_prep_x<<<10240, 256, 0, stream>>>(x, len, xf);
  k_prep_w<<<1856, 256, 0, stream>>>(wp, whp, wxp, W1, W2, w1t, w2t);
  k_rec<<<256, 256, 0, stream>>>(whp, wxp, xf, wp, len, hpub, ho, pool);
  k_logits<<<8192, 256, 0, stream>>>(ho, w1t, w2t, b1, b2, lgt);
  k_crf<<<32, 256, 0, stream>>>(lgt, labels, len, trans1, trans2, (float*)d_out);
}

// Round 12
// 3681.926 us; speedup vs baseline: 984.1317x; 984.1317x over previous
//
#include <hip/hip_runtime.h>
#include <cstdint>
#include <cstddef>

#define B_ 64
#define T_ 512
#define D_ 300
#define DP_ 320
#define H_ 256
#define G4_ 1024
#define NL_ 6

typedef float f32x4 __attribute__((ext_vector_type(4)));
typedef __bf16 bf16x8 __attribute__((ext_vector_type(8)));

struct WPtrs { const float* W[NL_]; const float* Bv[NL_]; };

__device__ __forceinline__ unsigned short f2bf(float f){
  unsigned int u = __float_as_uint(f);
  unsigned int r = u + 0x7FFFu + ((u >> 16) & 1u);
  return (unsigned short)(r >> 16);
}
__device__ __forceinline__ float bf2f(unsigned int s){
  return __uint_as_float((s & 0xFFFFu) << 16);
}
__device__ __forceinline__ float fast_sig(float x){
  return __builtin_amdgcn_rcpf(1.f + __builtin_amdgcn_exp2f(-1.4426950408889634f * x));
}
__device__ __forceinline__ float fast_tanh(float x){
  return 1.f - 2.f * __builtin_amdgcn_rcpf(1.f + __builtin_amdgcn_exp2f(2.8853900817779268f * x));
}
__device__ __forceinline__ void store8bf(unsigned short* p, const unsigned short v[8]){
  uint4 u;
  u.x = (unsigned)v[0] | ((unsigned)v[1] << 16);
  u.y = (unsigned)v[2] | ((unsigned)v[3] << 16);
  u.z = (unsigned)v[4] | ((unsigned)v[5] << 16);
  u.w = (unsigned)v[6] | ((unsigned)v[7] << 16);
  *(uint4*)p = u;
}

// ---------- Phase 0a: x -> bf16 A-frag layout xf[dir][t][bt4][kt10][lane64][e8] ----------
__global__ void k_prep_x(const float* __restrict__ x, const int* __restrict__ len,
                         unsigned short* __restrict__ xf){
  int idx = blockIdx.x * 256 + threadIdx.x;    // over 2*512*4*10*64 = 2,621,440
  int lane = idx & 63;
  int kt = (idx >> 6) % 10;
  int r1 = idx / 640;
  int bt = r1 & 3;
  int r2 = r1 >> 2;
  int t = r2 & 511;
  int dir = r2 >> 9;
  if (dir >= 2) return;
  int bb = bt * 16 + (lane & 15);
  int k0 = kt * 32 + (lane >> 4) * 8;
  int L = len[bb];
  int tsrc = dir ? ((t < L) ? (L - 1 - t) : t) : t;
  const float* xs = x + ((size_t)bb * T_ + tsrc) * D_;
  unsigned short v[8];
  #pragma unroll
  for (int e = 0; e < 8; e++){
    int k = k0 + e;
    v[e] = f2bf(k < D_ ? xs[k] : 0.f);
  }
  store8bf(xf + ((size_t)idx) * 8, v);
}

// ---------- Phase 0b: prepack weights (frag indexing HW-verified rounds 2-6) ----------
__global__ void k_prep_w(WPtrs wp, unsigned short* __restrict__ whp,
                         unsigned short* __restrict__ wxp,
                         const float* __restrict__ W1, const float* __restrict__ W2,
                         float* __restrict__ w1t, float* __restrict__ w2t){
  int idx = blockIdx.x * 256 + threadIdx.x;
  const int nWh = NL_ * 16 * 4 * 8 * 64;   // 196608
  const int nWx = NL_ * 16 * 10 * 4 * 64;  // 245760
  if (idx < nWh){
    int lane = idx & 63, kt = (idx >> 6) & 7, g = (idx >> 9) & 3, s = (idx >> 11) & 15, l = idx >> 15;
    int col = g * 256 + s * 16 + (lane & 15);
    int k0 = kt * 32 + (lane >> 4) * 8;
    const float* W = wp.W[l];
    unsigned short v[8];
    #pragma unroll
    for (int e = 0; e < 8; e++) v[e] = f2bf(W[(size_t)(D_ + k0 + e) * G4_ + col]);
    store8bf(whp + ((((size_t)(l * 16 + s) * 4 + g) * 8 + kt) * 64 + lane) * 8, v);
  } else if (idx < nWh + nWx){
    int i2 = idx - nWh;
    int lane = i2 & 63;
    int g = (i2 >> 6) & 3;
    int r = i2 >> 8;
    int kt = r % 10;
    int r2 = r / 10;
    int s = r2 & 15, l = r2 >> 4;
    int col = g * 256 + s * 16 + (lane & 15);
    int k0 = kt * 32 + (lane >> 4) * 8;
    const float* W = wp.W[l];
    unsigned short v[8];
    #pragma unroll
    for (int e = 0; e < 8; e++){
      int k = k0 + e;
      v[e] = f2bf(k < D_ ? W[(size_t)k * G4_ + col] : 0.f);
    }
    store8bf(wxp + ((((size_t)(l * 16 + s) * 10 + kt) * 4 + g) * 64 + lane) * 8, v);
  } else if (idx < nWh + nWx + 16384){
    int i2 = idx - nWh - nWx;
    int h = i2 & 1023, k = i2 >> 10;
    w1t[k * G4_ + h] = (k < 10) ? W1[h * 10 + k] : 0.f;
  } else if (idx < nWh + nWx + 32768){
    int i2 = idx - nWh - nWx - 16384;
    int h = i2 & 1023, k = i2 >> 10;
    w2t[k * G4_ + h] = (k < 12) ? W2[h * 12 + k] : 0.f;
  }
}

// hpub region (per l, slot, wave): 2048 u64 = 16 rows x 256 units as tagged u32 pairs,
// consumer-frag ordered. Transport: AGENT-scope relaxed atomics (r3/r4/r5-verified correct
// under spin on this chip; sc0 spin-loads hit stale L1 forever, buffer_inv drops dirty L2).
// h-phase code below is r5 VERBATIM (the 2294us passing anchor).
#define LOADH() \
  { _Pragma("unroll") \
    for (int kt = 0; kt < 8; kt++) \
      _Pragma("unroll") \
      for (int jj = 0; jj < 4; jj++) \
        hq[kt][jj] = __hip_atomic_load(hreg + (kt * 4 + jj) * 64 + lane, \
                                       __ATOMIC_RELAXED, __HIP_MEMORY_SCOPE_AGENT); \
  }

#define UNPACKH() \
  { accor = 0u; \
    _Pragma("unroll") \
    for (int kt = 0; kt < 8; kt++){ \
      union { unsigned u[4]; bf16x8 v; } uu; \
      _Pragma("unroll") \
      for (int jj = 0; jj < 4; jj++){ \
        unsigned lo = (unsigned)hq[kt][jj]; \
        unsigned hi = (unsigned)(hq[kt][jj] >> 32); \
        uu.u[jj] = __builtin_amdgcn_perm(hi, lo, 0x05040100u); \
        accor |= __builtin_amdgcn_perm(hi, lo, 0x07060302u) ^ cmpw; \
      } \
      Ah[kt] = uu.v; \
    } }

#define HMFMA() \
  { _Pragma("unroll") \
    for (int g = 0; g < 4; g++) acc[g] = accX[g]; \
    _Pragma("unroll") \
    for (int kt = 0; kt < 8; kt++) \
      _Pragma("unroll") \
      for (int g = 0; g < 4; g++) \
        acc[g] = __builtin_amdgcn_mfma_f32_16x16x32_bf16(Ah[kt], Bh[g][kt], acc[g], 0, 0, 0); \
  }

// One LSTM step — r5 ordering exactly: x-MFMA -> LOADH(speculative) -> UNPACK+HMFMA ->
// stale-check/retry -> gates -> publish -> ho. Only delta vs r5: x operands come from
// prefetched registers PC, and PF is refilled for the next step (plain loads, new regs).
#define STEP2(TT, PC, PF) do { \
    if ((TT) + 1 < T_){ \
      _Pragma("unroll") \
      for (int kt = 0; kt < 10; kt++) \
        PF[kt] = *(const bf16x8*)(xw + (size_t)((TT) + 1) * 20480 + kt * 512); \
    } \
    f32x4 accX[4]; \
    _Pragma("unroll") \
    for (int g = 0; g < 4; g++){ accX[g].x = 0.f; accX[g].y = 0.f; accX[g].z = 0.f; accX[g].w = 0.f; } \
    _Pragma("unroll") \
    for (int kt = 0; kt < 10; kt++){ \
      _Pragma("unroll") \
      for (int g = 0; g < 4; g++){ \
        bf16x8 Bxf = *(const bf16x8*)(bxs + ((size_t)(kt * 4 + g) * 64) * 8); \
        accX[g] = __builtin_amdgcn_mfma_f32_16x16x32_bf16(PC[kt], Bxf, accX[g], 0, 0, 0); \
      } \
    } \
    f32x4 acc[4]; \
    if ((TT) > 0){ \
      const unsigned long long* hreg = \
          hpub + (((size_t)(l * 2 + (((TT) - 1) & 1)) * 4 + w) * 2048); \
      unsigned long long hq[8][4]; \
      bf16x8 Ah[8]; \
      unsigned accor; \
      const unsigned cmpw = ((unsigned)((TT) - 1)) * 0x00010001u; \
      LOADH(); \
      UNPACKH(); \
      HMFMA(); \
      bool stale = __any(accor != 0); \
      int tries = 0; \
      while (stale && tries < 8192){ \
        tries++; \
        __builtin_amdgcn_s_sleep(1); \
        LOADH(); \
        UNPACKH(); \
        stale = __any(accor != 0); \
        if (!stale){ HMFMA(); } \
      } \
    } else { \
      _Pragma("unroll") \
      for (int g = 0; g < 4; g++) acc[g] = accX[g]; \
    } \
    unsigned short hpb[4], hov[4]; \
    _Pragma("unroll") \
    for (int r = 0; r < 4; r++){ \
      float gi = acc[0][r] + bias[0], gj = acc[1][r] + bias[1]; \
      float gf = acc[2][r] + bias[2], go = acc[3][r] + bias[3]; \
      float cn = fast_sig(gf + 1.f) * c4[r] + fast_sig(gi) * fast_tanh(gj); \
      float hn = fast_sig(go) * fast_tanh(cn); \
      bool m = ((TT) < Lr[r]); \
      c4[r] = m ? cn : c4[r]; \
      h4[r] = m ? hn : h4[r]; \
      hpb[r] = f2bf(h4[r]); \
      hov[r] = f2bf(m ? hn : 0.f); \
    } \
    { unsigned tagt = ((unsigned)(TT)) << 16; \
      _Pragma("unroll") \
      for (int rr = 0; rr < 4; rr++) \
        lds_pub[lbase + (g2 * 4 + rr) * 2] = tagt | (unsigned)hpb[rr]; \
      unsigned long long* hrego = hpub + (((size_t)(l * 2 + ((TT) & 1)) * 4 + w) * 2048); \
      __hip_atomic_store(hrego + so0,      lds64[rb0], __ATOMIC_RELAXED, __HIP_MEMORY_SCOPE_AGENT); \
      __hip_atomic_store(hrego + so0 + 16, lds64[rb1], __ATOMIC_RELAXED, __HIP_MEMORY_SCOPE_AGENT); } \
    _Pragma("unroll") \
    for (int rr = 0; rr < 4; rr++){ \
      int bb2 = w * 16 + (lane >> 4) * 4 + rr; \
      int tdst = dir ? (((TT) < Lr[rr]) ? (Lr[rr] - 1 - (TT)) : (TT)) : (TT); \
      ho[(((size_t)l * B_ + bb2) * T_ + tdst) * H_ + unit] = hov[rr]; \
    } \
  } while (0)

// ---------- Phase 1: fused recurrent LSTM; r5 sync structure + xf register prefetch ----------
__global__ __launch_bounds__(256, 1) void k_rec(
    const unsigned short* __restrict__ whp, const unsigned short* __restrict__ wxp,
    const unsigned short* __restrict__ xf, WPtrs wp, const int* __restrict__ len,
    unsigned long long* __restrict__ hpub, unsigned short* __restrict__ ho){
  int l = blockIdx.x >> 4;
  int s = blockIdx.x & 15;
  int tid = threadIdx.x, lane = tid & 63, w = tid >> 6;
  const int dir = l & 1;

  __shared__ unsigned int lds_pub[1024];   // wave-private redistribute

  // resident Wh B-frags [gate][kt] (128 VGPRs)
  bf16x8 Bh[4][8];
  #pragma unroll
  for (int g = 0; g < 4; g++)
    #pragma unroll
    for (int kt = 0; kt < 8; kt++)
      Bh[g][kt] = *(const bf16x8*)(whp + ((((size_t)(l * 16 + s) * 4 + g) * 8 + kt) * 64 + lane) * 8);
  // Wx streamed from L2 per use (r6-verified form; keeps VGPRs for the P0/P1 prefetch)
  const unsigned short* bxs = wxp + (size_t)(l * 16 + s) * 10 * 4 * 64 * 8 + (size_t)lane * 8;

  float bias[4];
  #pragma unroll
  for (int g = 0; g < 4; g++) bias[g] = wp.Bv[l][g * 256 + s * 16 + (lane & 15)];

  float c4[4] = {0.f, 0.f, 0.f, 0.f};
  float h4[4] = {0.f, 0.f, 0.f, 0.f};
  int Lr[4];
  #pragma unroll
  for (int r = 0; r < 4; r++) Lr[r] = len[w * 16 + (lane >> 4) * 4 + r];

  int unit = s * 16 + (lane & 15);
  const int kt_s = s >> 1, qc0 = (s & 1) * 2;
  const int rp = lane & 15, g2 = lane >> 4;
  const int pjj = (rp >> 1) & 3, pqh = rp >> 3, ppp = rp & 1;
  const int lbase = w * 256 + (pjj * 2 + pqh) * 32 + ppp;
  unsigned long long* lds64 = (unsigned long long*)lds_pub;
  const int rb0 = w * 128 + ((lane >> 4) * 2 + 0) * 16 + (lane & 15);
  const int rb1 = rb0 + 16;
  const size_t so0 = (size_t)(kt_s * 4 + (lane >> 4)) * 64 + qc0 * 16 + (lane & 15);

  // xf per-wave base; element (t,kt) at xw + t*20480 + kt*512 (shorts) — r2-r6-verified layout
  const unsigned short* xw = xf + ((size_t)(dir * T_) * 4 + w) * 5120 + lane * 8;

  // prologue: P0 <- xf[0]
  bf16x8 P0[10], P1[10];
  #pragma unroll
  for (int kt = 0; kt < 10; kt++)
    P0[kt] = *(const bf16x8*)(xw + kt * 512);

  #pragma unroll 1
  for (int t2 = 0; t2 < T_; t2 += 2){
    STEP2(t2,     P0, P1);
    STEP2(t2 + 1, P1, P0);
  }
}

// ---------- Phase 3: logits = concat(ho) @ W + b  (wave per (b,t)) ----------
__global__ void k_logits(const unsigned short* __restrict__ ho,
                         const float* __restrict__ w1t, const float* __restrict__ w2t,
                         const float* __restrict__ b1, const float* __restrict__ b2,
                         float* __restrict__ lgt){
  int gid = blockIdx.x * 4 + (threadIdx.x >> 6);   // 0..32767 = b*512+t
  int lane = threadIdx.x & 63;
  int b = gid >> 9, t = gid & 511;
  float hv[6][4];
  #pragma unroll
  for (int lgi = 0; lgi < 6; lgi++){
    const unsigned short* hrow = ho + (((size_t)lgi * B_ + b) * T_ + t) * H_;
    uint2 u = *(const uint2*)(hrow + lane * 4);
    hv[lgi][0] = bf2f(u.x); hv[lgi][1] = bf2f(u.x >> 16);
    hv[lgi][2] = bf2f(u.y); hv[lgi][3] = bf2f(u.y >> 16);
  }
  float s1[10], s2[12];
  #pragma unroll
  for (int k = 0; k < 10; k++) s1[k] = 0.f;
  #pragma unroll
  for (int k = 0; k < 12; k++) s2[k] = 0.f;
  const int seg1[4] = {0, 1, 4, 5};
  const int seg2[4] = {2, 3, 4, 5};
  #pragma unroll
  for (int k = 0; k < 10; k++){
    #pragma unroll
    for (int ii = 0; ii < 4; ii++){
      float4 wv = *(const float4*)(w1t + k * G4_ + ii * 256 + lane * 4);
      int lgi = seg1[ii];
      s1[k] += hv[lgi][0] * wv.x + hv[lgi][1] * wv.y + hv[lgi][2] * wv.z + hv[lgi][3] * wv.w;
    }
  }
  #pragma unroll
  for (int k = 0; k < 12; k++){
    #pragma unroll
    for (int ii = 0; ii < 4; ii++){
      float4 wv = *(const float4*)(w2t + k * G4_ + ii * 256 + lane * 4);
      int lgi = seg2[ii];
      s2[k] += hv[lgi][0] * wv.x + hv[lgi][1] * wv.y + hv[lgi][2] * wv.z + hv[lgi][3] * wv.w;
    }
  }
  #pragma unroll
  for (int k = 0; k < 10; k++)
    #pragma unroll
    for (int d = 1; d < 64; d <<= 1) s1[k] += __shfl_xor(s1[k], d, 64);
  #pragma unroll
  for (int k = 0; k < 12; k++)
    #pragma unroll
    for (int d = 1; d < 64; d <<= 1) s2[k] += __shfl_xor(s2[k], d, 64);
  if (lane == 0){
    float* o1 = lgt + ((size_t)(0 * B_ + b) * T_ + t) * 16;
    float* o2 = lgt + ((size_t)(1 * B_ + b) * T_ + t) * 16;
    #pragma unroll
    for (int k = 0; k < 10; k++) o1[k] = s1[k] + b1[k];
    #pragma unroll
    for (int k = 0; k < 12; k++) o2[k] = s2[k] + b2[k];
  }
}

// ---------- Phase 4: CRF NLL (wave per (task, b)) ----------
__global__ void k_crf(const float* __restrict__ lgt, const int* __restrict__ labels,
                      const int* __restrict__ len, const float* __restrict__ trans1,
                      const float* __restrict__ trans2, float* __restrict__ out){
  int gid = blockIdx.x * 4 + (threadIdx.x >> 6);    // 0..127
  int lane = threadIdx.x & 63;
  int tau = gid >> 6;
  int b = gid & 63;
  int K = tau ? 12 : 10;
  const float* tr = tau ? trans2 : trans1;
  const float* lgp = lgt + (size_t)(tau * B_ + b) * T_ * 16;
  int L = len[b];
  int k2 = lane & 15;
  const float LOG2E = 1.4426950408889634f;
  const float LN2 = 0.6931471805599453f;
  float Et[12];
  #pragma unroll
  for (int k1 = 0; k1 < 12; k1++)
    Et[k1] = (k1 < K && k2 < K) ? __builtin_amdgcn_exp2f(LOG2E * tr[k1 * K + k2]) : 0.f;
  float alpha = (k2 < K) ? lgp[k2] : -1e30f;
  for (int t = 1; t < L; t++){
    float m = alpha;
    #pragma unroll
    for (int d = 1; d < 16; d <<= 1) m = fmaxf(m, __shfl_xor(m, d, 16));
    float e = __builtin_amdgcn_exp2f(LOG2E * (alpha - m));
    float ss = 0.f;
    #pragma unroll
    for (int k1 = 0; k1 < 12; k1++)
      ss += __shfl(e, k1, 16) * Et[k1];
    float na = m + LN2 * __builtin_amdgcn_logf(ss) + lgp[t * 16 + k2];
    alpha = (k2 < K) ? na : -1e30f;
  }
  float m2 = alpha;
  #pragma unroll
  for (int d = 1; d < 16; d <<= 1) m2 = fmaxf(m2, __shfl_xor(m2, d, 16));
  float e2 = __builtin_amdgcn_exp2f(LOG2E * (alpha - m2));
  #pragma unroll
  for (int d = 1; d < 16; d <<= 1) e2 += __shfl_xor(e2, d, 16);
  float logZ = m2 + LN2 * __builtin_amdgcn_logf(e2);
  float us = 0.f;
  const int* lab = labels + b * T_;
  for (int t0 = lane; t0 < L; t0 += 64){
    int la = lab[t0];
    us += lgp[t0 * 16 + la];
    if (t0 >= 1) us += tr[lab[t0 - 1] * K + la];
  }
  #pragma unroll
  for (int d = 1; d < 64; d <<= 1) us += __shfl_xor(us, d, 64);
  if (lane == 0) out[tau * B_ + b] = logZ - us;
}

extern "C" void kernel_launch(void* const* d_in, const int* in_sizes, int n_in,
                              void* d_out, int out_size, void* d_ws, size_t ws_size,
                              hipStream_t stream){
  const float* x = (const float*)d_in[0];
  const int* len = (const int*)d_in[1];
  const int* labels = (const int*)d_in[2];
  WPtrs wp;
  for (int l = 0; l < NL_; l++){
    wp.W[l] = (const float*)d_in[3 + 2 * l];
    wp.Bv[l] = (const float*)d_in[4 + 2 * l];
  }
  const float* W1 = (const float*)d_in[15];
  const float* b1 = (const float*)d_in[16];
  const float* W2 = (const float*)d_in[17];
  const float* b2 = (const float*)d_in[18];
  const float* trans1 = (const float*)d_in[19];
  const float* trans2 = (const float*)d_in[20];

  char* ws = (char*)d_ws;
  const size_t SZ_HPUB = (size_t)NL_ * 2 * 4 * 2048 * 8;      //   786,432
  const size_t O_WHP = SZ_HPUB;
  const size_t SZ_WHP = (size_t)NL_ * H_ * G4_ * 2;           // 3,145,728
  const size_t O_WXP = O_WHP + SZ_WHP;
  const size_t SZ_WXP = (size_t)NL_ * DP_ * G4_ * 2;          // 3,932,160
  const size_t O_XF  = O_WXP + SZ_WXP;
  const size_t SZ_XF = 2ull * T_ * 4 * 10 * 64 * 8 * 2;       // 41,943,040
  const size_t O_HO  = O_XF + SZ_XF;
  const size_t SZ_HO = (size_t)NL_ * B_ * T_ * H_ * 2;        // 100,663,296
  const size_t O_LGT = O_HO + SZ_HO;
  const size_t SZ_LGT = 2ull * B_ * T_ * 16 * 4;              //   8,388,608
  const size_t O_W1T = O_LGT + SZ_LGT;
  const size_t O_W2T = O_W1T + 65536;

  unsigned long long* hpub = (unsigned long long*)(ws + 0);
  unsigned short* whp = (unsigned short*)(ws + O_WHP);
  unsigned short* wxp = (unsigned short*)(ws + O_WXP);
  unsigned short* xf  = (unsigned short*)(ws + O_XF);
  unsigned short* ho  = (unsigned short*)(ws + O_HO);
  float* lgt = (float*)(ws + O_LGT);
  float* w1t = (float*)(ws + O_W1T);
  float* w2t = (float*)(ws + O_W2T);

  // invalidate all tags (0xFFFF != any t in [0,512)) — graph-replay safety
  hipMemsetAsync(hpub, 0xFF, SZ_HPUB, stream);
  k_prep_x<<<10240, 256, 0, stream>>>(x, len, xf);
  k_prep_w<<<1856, 256, 0, stream>>>(wp, whp, wxp, W1, W2, w1t, w2t);
  k_rec<<<96, 256, 0, stream>>>(whp, wxp, xf, wp, len, hpub, ho);
  k_logits<<<8192, 256, 0, stream>>>(ho, w1t, w2t, b1, b2, lgt);
  k_crf<<<32, 256, 0, stream>>>(lgt, labels, len, trans1, trans2, (float*)d_out);
}

// Round 13
// 2619.248 us; speedup vs baseline: 1383.4120x; 1.4057x over previous
//
#include <hip/hip_runtime.h>
#include <cstdint>
#include <cstddef>

#define B_ 64
#define T_ 512
#define D_ 300
#define DP_ 320
#define H_ 256
#define G4_ 1024
#define NL_ 6

typedef float f32x4 __attribute__((ext_vector_type(4)));
typedef __bf16 bf16x8 __attribute__((ext_vector_type(8)));

struct WPtrs { const float* W[NL_]; const float* Bv[NL_]; };

__device__ __forceinline__ unsigned short f2bf(float f){
  unsigned int u = __float_as_uint(f);
  unsigned int r = u + 0x7FFFu + ((u >> 16) & 1u);
  return (unsigned short)(r >> 16);
}
__device__ __forceinline__ float bf2f(unsigned int s){
  return __uint_as_float((s & 0xFFFFu) << 16);
}
__device__ __forceinline__ float fast_sig(float x){
  return __builtin_amdgcn_rcpf(1.f + __builtin_amdgcn_exp2f(-1.4426950408889634f * x));
}
__device__ __forceinline__ float fast_tanh(float x){
  return 1.f - 2.f * __builtin_amdgcn_rcpf(1.f + __builtin_amdgcn_exp2f(2.8853900817779268f * x));
}
__device__ __forceinline__ void store8bf(unsigned short* p, const unsigned short v[8]){
  uint4 u;
  u.x = (unsigned)v[0] | ((unsigned)v[1] << 16);
  u.y = (unsigned)v[2] | ((unsigned)v[3] << 16);
  u.z = (unsigned)v[4] | ((unsigned)v[5] << 16);
  u.w = (unsigned)v[6] | ((unsigned)v[7] << 16);
  *(uint4*)p = u;
}

// ---------- Phase 0a: x -> bf16 A-frag layout xf[dir][t][bt4][kt10][lane64][e8] ----------
__global__ void k_prep_x(const float* __restrict__ x, const int* __restrict__ len,
                         unsigned short* __restrict__ xf){
  int idx = blockIdx.x * 256 + threadIdx.x;    // over 2*512*4*10*64 = 2,621,440
  int lane = idx & 63;
  int kt = (idx >> 6) % 10;
  int r1 = idx / 640;
  int bt = r1 & 3;
  int r2 = r1 >> 2;
  int t = r2 & 511;
  int dir = r2 >> 9;
  if (dir >= 2) return;
  int bb = bt * 16 + (lane & 15);
  int k0 = kt * 32 + (lane >> 4) * 8;
  int L = len[bb];
  int tsrc = dir ? ((t < L) ? (L - 1 - t) : t) : t;
  const float* xs = x + ((size_t)bb * T_ + tsrc) * D_;
  unsigned short v[8];
  #pragma unroll
  for (int e = 0; e < 8; e++){
    int k = k0 + e;
    v[e] = f2bf(k < D_ ? xs[k] : 0.f);
  }
  store8bf(xf + ((size_t)idx) * 8, v);
}

// ---------- Phase 0b: prepack weights (frag indexing HW-verified rounds 2-12) ----------
__global__ void k_prep_w(WPtrs wp, unsigned short* __restrict__ whp,
                         unsigned short* __restrict__ wxp,
                         const float* __restrict__ W1, const float* __restrict__ W2,
                         float* __restrict__ w1t, float* __restrict__ w2t){
  int idx = blockIdx.x * 256 + threadIdx.x;
  const int nWh = NL_ * 16 * 4 * 8 * 64;   // 196608
  const int nWx = NL_ * 16 * 10 * 4 * 64;  // 245760
  if (idx < nWh){
    int lane = idx & 63, kt = (idx >> 6) & 7, g = (idx >> 9) & 3, s = (idx >> 11) & 15, l = idx >> 15;
    int col = g * 256 + s * 16 + (lane & 15);
    int k0 = kt * 32 + (lane >> 4) * 8;
    const float* W = wp.W[l];
    unsigned short v[8];
    #pragma unroll
    for (int e = 0; e < 8; e++) v[e] = f2bf(W[(size_t)(D_ + k0 + e) * G4_ + col]);
    store8bf(whp + ((((size_t)(l * 16 + s) * 4 + g) * 8 + kt) * 64 + lane) * 8, v);
  } else if (idx < nWh + nWx){
    int i2 = idx - nWh;
    int lane = i2 & 63;
    int g = (i2 >> 6) & 3;
    int r = i2 >> 8;
    int kt = r % 10;
    int r2 = r / 10;
    int s = r2 & 15, l = r2 >> 4;
    int col = g * 256 + s * 16 + (lane & 15);
    int k0 = kt * 32 + (lane >> 4) * 8;
    const float* W = wp.W[l];
    unsigned short v[8];
    #pragma unroll
    for (int e = 0; e < 8; e++){
      int k = k0 + e;
      v[e] = f2bf(k < D_ ? W[(size_t)k * G4_ + col] : 0.f);
    }
    store8bf(wxp + ((((size_t)(l * 16 + s) * 10 + kt) * 4 + g) * 64 + lane) * 8, v);
  } else if (idx < nWh + nWx + 16384){
    int i2 = idx - nWh - nWx;
    int h = i2 & 1023, k = i2 >> 10;
    w1t[k * G4_ + h] = (k < 10) ? W1[h * 10 + k] : 0.f;
  } else if (idx < nWh + nWx + 32768){
    int i2 = idx - nWh - nWx - 16384;
    int h = i2 & 1023, k = i2 >> 10;
    w2t[k * G4_ + h] = (k < 12) ? W2[h * 12 + k] : 0.f;
  }
}

// hpub region (per l, slot, wave): 2048 u64 = 16 rows x 256 units as tagged u32 pairs,
// consumer-frag ordered (HW-verified r5/r12). Transport: AGENT-scope relaxed atomics —
// the only spin transport verified correct on this chip (sc0 re-hits stale L1;
// buffer_inv drops dirty L2). This k_rec is the r5 2294us anchor VERBATIM except
// the retry-sleep policy (hot-spin first 6 tries).
#define LOADH() \
  { _Pragma("unroll") \
    for (int kt = 0; kt < 8; kt++) \
      _Pragma("unroll") \
      for (int jj = 0; jj < 4; jj++) \
        hq[kt][jj] = __hip_atomic_load(hreg + (kt * 4 + jj) * 64 + lane, \
                                       __ATOMIC_RELAXED, __HIP_MEMORY_SCOPE_AGENT); \
  }

#define UNPACKH() \
  { accor = 0u; \
    _Pragma("unroll") \
    for (int kt = 0; kt < 8; kt++){ \
      union { unsigned u[4]; bf16x8 v; } uu; \
      _Pragma("unroll") \
      for (int jj = 0; jj < 4; jj++){ \
        unsigned lo = (unsigned)hq[kt][jj]; \
        unsigned hi = (unsigned)(hq[kt][jj] >> 32); \
        uu.u[jj] = __builtin_amdgcn_perm(hi, lo, 0x05040100u); \
        accor |= __builtin_amdgcn_perm(hi, lo, 0x07060302u) ^ cmpw; \
      } \
      Ah[kt] = uu.v; \
    } }

#define HMFMA() \
  { _Pragma("unroll") \
    for (int g = 0; g < 4; g++) acc[g] = accX[g]; \
    _Pragma("unroll") \
    for (int kt = 0; kt < 8; kt++) \
      _Pragma("unroll") \
      for (int g = 0; g < 4; g++) \
        acc[g] = __builtin_amdgcn_mfma_f32_16x16x32_bf16(Ah[kt], Bh[g][kt], acc[g], 0, 0, 0); \
  }

// ---------- Phase 1: fused recurrent LSTM; tag sync; coalesced frag-ordered exchange ----------
__global__ __launch_bounds__(256, 1) void k_rec(
    const unsigned short* __restrict__ whp, const unsigned short* __restrict__ wxp,
    const unsigned short* __restrict__ xf, WPtrs wp, const int* __restrict__ len,
    unsigned long long* __restrict__ hpub, unsigned short* __restrict__ ho){
  int l = blockIdx.x >> 4;
  int s = blockIdx.x & 15;
  int tid = threadIdx.x, lane = tid & 63, w = tid >> 6;
  const int dir = l & 1;

  __shared__ unsigned int lds_pub[1024];   // [wave4][jj4][qh2][r16][p2] u32 — wave-private

  bf16x8 Bh[4][8];
  #pragma unroll
  for (int g = 0; g < 4; g++)
    #pragma unroll
    for (int kt = 0; kt < 8; kt++)
      Bh[g][kt] = *(const bf16x8*)(whp + ((((size_t)(l * 16 + s) * 4 + g) * 8 + kt) * 64 + lane) * 8);
  bf16x8 Bx[10][4];
  #pragma unroll
  for (int kt = 0; kt < 10; kt++)
    #pragma unroll
    for (int g = 0; g < 4; g++)
      Bx[kt][g] = *(const bf16x8*)(wxp + ((((size_t)(l * 16 + s) * 10 + kt) * 4 + g) * 64 + lane) * 8);

  float bias[4];
  #pragma unroll
  for (int g = 0; g < 4; g++) bias[g] = wp.Bv[l][g * 256 + s * 16 + (lane & 15)];

  float c4[4] = {0.f, 0.f, 0.f, 0.f};
  float h4[4] = {0.f, 0.f, 0.f, 0.f};
  int Lr[4];
  #pragma unroll
  for (int r = 0; r < 4; r++) Lr[r] = len[w * 16 + (lane >> 4) * 4 + r];

  int unit = s * 16 + (lane & 15);
  const int kt_s = s >> 1, qc0 = (s & 1) * 2;
  // producer lane constants for LDS redistribute
  const int rp = lane & 15, g2 = lane >> 4;
  const int pjj = (rp >> 1) & 3, pqh = rp >> 3, ppp = rp & 1;
  const int lbase = w * 256 + (pjj * 2 + pqh) * 32 + ppp;
  unsigned long long* lds64 = (unsigned long long*)lds_pub;
  const int rb0 = w * 128 + ((lane >> 4) * 2 + 0) * 16 + (lane & 15);
  const int rb1 = rb0 + 16;
  const size_t so0 = (size_t)(kt_s * 4 + (lane >> 4)) * 64 + qc0 * 16 + (lane & 15);

  for (int t = 0; t < T_; t++){
    // ---- x-phase: accX = x_t @ Wx ----
    f32x4 accX[4];
    #pragma unroll
    for (int g = 0; g < 4; g++){ accX[g].x = 0.f; accX[g].y = 0.f; accX[g].z = 0.f; accX[g].w = 0.f; }
    const unsigned short* xt = xf + (((size_t)(dir * T_ + t) * 4 + w) * 10) * 512;
    #pragma unroll
    for (int kt = 0; kt < 10; kt++){
      bf16x8 Ax = *(const bf16x8*)(xt + (size_t)kt * 512 + lane * 8);
      #pragma unroll
      for (int g = 0; g < 4; g++)
        accX[g] = __builtin_amdgcn_mfma_f32_16x16x32_bf16(Ax, Bx[kt][g], accX[g], 0, 0, 0);
    }
    // ---- h-phase: coalesced tagged load + speculative MFMA + tag-check ----
    f32x4 acc[4];
    if (t > 0){
      const unsigned long long* hreg = hpub + (((size_t)(l * 2 + ((t - 1) & 1)) * 4 + w) * 2048);
      unsigned long long hq[8][4];
      bf16x8 Ah[8];
      unsigned accor;
      const unsigned cmpw = ((unsigned)(t - 1)) * 0x00010001u;
      LOADH();
      UNPACKH();
      HMFMA();                       // speculative: check overlaps MFMA
      bool stale = __any(accor != 0);
      int tries = 0;
      while (stale && tries < 8192){
        tries++;
        if (tries > 6) __builtin_amdgcn_s_sleep(1);   // hot-spin first 6 (agent loads always fresh)
        LOADH();
        UNPACKH();
        stale = __any(accor != 0);
        if (!stale){ HMFMA(); }
      }
    } else {
      #pragma unroll
      for (int g = 0; g < 4; g++) acc[g] = accX[g];
    }
    // ---- gates ----
    unsigned short hpb[4], hov[4];
    #pragma unroll
    for (int r = 0; r < 4; r++){
      float gi = acc[0][r] + bias[0], gj = acc[1][r] + bias[1];
      float gf = acc[2][r] + bias[2], go = acc[3][r] + bias[3];
      float cn = fast_sig(gf + 1.f) * c4[r] + fast_sig(gi) * fast_tanh(gj);
      float hn = fast_sig(go) * fast_tanh(cn);
      bool m = (t < Lr[r]);
      c4[r] = m ? cn : c4[r];
      h4[r] = m ? hn : h4[r];
      hpb[r] = f2bf(h4[r]);
      hov[r] = f2bf(m ? hn : 0.f);
    }
    // ---- publish: wave-private LDS redistribute -> 2 coalesced u64 stores/lane ----
    unsigned tagt = ((unsigned)t) << 16;
    #pragma unroll
    for (int rr = 0; rr < 4; rr++)
      lds_pub[lbase + (g2 * 4 + rr) * 2] = tagt | (unsigned)hpb[rr];
    unsigned long long* hrego = hpub + (((size_t)(l * 2 + (t & 1)) * 4 + w) * 2048);
    __hip_atomic_store(hrego + so0,      lds64[rb0], __ATOMIC_RELAXED, __HIP_MEMORY_SCOPE_AGENT);
    __hip_atomic_store(hrego + so0 + 16, lds64[rb1], __ATOMIC_RELAXED, __HIP_MEMORY_SCOPE_AGENT);
    // ---- ho writes: ho[l][b][t][unit] ----
    #pragma unroll
    for (int rr = 0; rr < 4; rr++){
      int b = w * 16 + (lane >> 4) * 4 + rr;
      int tdst = dir ? ((t < Lr[rr]) ? (Lr[rr] - 1 - t) : t) : t;
      ho[(((size_t)l * B_ + b) * T_ + tdst) * H_ + unit] = hov[rr];
    }
  }
}

// ---------- Phase 3: logits = concat(ho) @ W + b  (wave per (b,t)) ----------
__global__ void k_logits(const unsigned short* __restrict__ ho,
                         const float* __restrict__ w1t, const float* __restrict__ w2t,
                         const float* __restrict__ b1, const float* __restrict__ b2,
                         float* __restrict__ lgt){
  int gid = blockIdx.x * 4 + (threadIdx.x >> 6);   // 0..32767 = b*512+t
  int lane = threadIdx.x & 63;
  int b = gid >> 9, t = gid & 511;
  float hv[6][4];
  #pragma unroll
  for (int lgi = 0; lgi < 6; lgi++){
    const unsigned short* hrow = ho + (((size_t)lgi * B_ + b) * T_ + t) * H_;
    uint2 u = *(const uint2*)(hrow + lane * 4);
    hv[lgi][0] = bf2f(u.x); hv[lgi][1] = bf2f(u.x >> 16);
    hv[lgi][2] = bf2f(u.y); hv[lgi][3] = bf2f(u.y >> 16);
  }
  float s1[10], s2[12];
  #pragma unroll
  for (int k = 0; k < 10; k++) s1[k] = 0.f;
  #pragma unroll
  for (int k = 0; k < 12; k++) s2[k] = 0.f;
  const int seg1[4] = {0, 1, 4, 5};
  const int seg2[4] = {2, 3, 4, 5};
  #pragma unroll
  for (int k = 0; k < 10; k++){
    #pragma unroll
    for (int ii = 0; ii < 4; ii++){
      float4 wv = *(const float4*)(w1t + k * G4_ + ii * 256 + lane * 4);
      int lgi = seg1[ii];
      s1[k] += hv[lgi][0] * wv.x + hv[lgi][1] * wv.y + hv[lgi][2] * wv.z + hv[lgi][3] * wv.w;
    }
  }
  #pragma unroll
  for (int k = 0; k < 12; k++){
    #pragma unroll
    for (int ii = 0; ii < 4; ii++){
      float4 wv = *(const float4*)(w2t + k * G4_ + ii * 256 + lane * 4);
      int lgi = seg2[ii];
      s2[k] += hv[lgi][0] * wv.x + hv[lgi][1] * wv.y + hv[lgi][2] * wv.z + hv[lgi][3] * wv.w;
    }
  }
  #pragma unroll
  for (int k = 0; k < 10; k++)
    #pragma unroll
    for (int d = 1; d < 64; d <<= 1) s1[k] += __shfl_xor(s1[k], d, 64);
  #pragma unroll
  for (int k = 0; k < 12; k++)
    #pragma unroll
    for (int d = 1; d < 64; d <<= 1) s2[k] += __shfl_xor(s2[k], d, 64);
  if (lane == 0){
    float* o1 = lgt + ((size_t)(0 * B_ + b) * T_ + t) * 16;
    float* o2 = lgt + ((size_t)(1 * B_ + b) * T_ + t) * 16;
    #pragma unroll
    for (int k = 0; k < 10; k++) o1[k] = s1[k] + b1[k];
    #pragma unroll
    for (int k = 0; k < 12; k++) o2[k] = s2[k] + b2[k];
  }
}

// ---------- Phase 4: CRF NLL (wave per (task, b)) ----------
__global__ void k_crf(const float* __restrict__ lgt, const int* __restrict__ labels,
                      const int* __restrict__ len, const float* __restrict__ trans1,
                      const float* __restrict__ trans2, float* __restrict__ out){
  int gid = blockIdx.x * 4 + (threadIdx.x >> 6);    // 0..127
  int lane = threadIdx.x & 63;
  int tau = gid >> 6;
  int b = gid & 63;
  int K = tau ? 12 : 10;
  const float* tr = tau ? trans2 : trans1;
  const float* lgp = lgt + (size_t)(tau * B_ + b) * T_ * 16;
  int L = len[b];
  int k2 = lane & 15;
  const float LOG2E = 1.4426950408889634f;
  const float LN2 = 0.6931471805599453f;
  float Et[12];
  #pragma unroll
  for (int k1 = 0; k1 < 12; k1++)
    Et[k1] = (k1 < K && k2 < K) ? __builtin_amdgcn_exp2f(LOG2E * tr[k1 * K + k2]) : 0.f;
  float alpha = (k2 < K) ? lgp[k2] : -1e30f;
  for (int t = 1; t < L; t++){
    float m = alpha;
    #pragma unroll
    for (int d = 1; d < 16; d <<= 1) m = fmaxf(m, __shfl_xor(m, d, 16));
    float e = __builtin_amdgcn_exp2f(LOG2E * (alpha - m));
    float ss = 0.f;
    #pragma unroll
    for (int k1 = 0; k1 < 12; k1++)
      ss += __shfl(e, k1, 16) * Et[k1];
    float na = m + LN2 * __builtin_amdgcn_logf(ss) + lgp[t * 16 + k2];
    alpha = (k2 < K) ? na : -1e30f;
  }
  float m2 = alpha;
  #pragma unroll
  for (int d = 1; d < 16; d <<= 1) m2 = fmaxf(m2, __shfl_xor(m2, d, 16));
  float e2 = __builtin_amdgcn_exp2f(LOG2E * (alpha - m2));
  #pragma unroll
  for (int d = 1; d < 16; d <<= 1) e2 += __shfl_xor(e2, d, 16);
  float logZ = m2 + LN2 * __builtin_amdgcn_logf(e2);
  float us = 0.f;
  const int* lab = labels + b * T_;
  for (int t0 = lane; t0 < L; t0 += 64){
    int la = lab[t0];
    us += lgp[t0 * 16 + la];
    if (t0 >= 1) us += tr[lab[t0 - 1] * K + la];
  }
  #pragma unroll
  for (int d = 1; d < 64; d <<= 1) us += __shfl_xor(us, d, 64);
  if (lane == 0) out[tau * B_ + b] = logZ - us;
}

extern "C" void kernel_launch(void* const* d_in, const int* in_sizes, int n_in,
                              void* d_out, int out_size, void* d_ws, size_t ws_size,
                              hipStream_t stream){
  const float* x = (const float*)d_in[0];
  const int* len = (const int*)d_in[1];
  const int* labels = (const int*)d_in[2];
  WPtrs wp;
  for (int l = 0; l < NL_; l++){
    wp.W[l] = (const float*)d_in[3 + 2 * l];
    wp.Bv[l] = (const float*)d_in[4 + 2 * l];
  }
  const float* W1 = (const float*)d_in[15];
  const float* b1 = (const float*)d_in[16];
  const float* W2 = (const float*)d_in[17];
  const float* b2 = (const float*)d_in[18];
  const float* trans1 = (const float*)d_in[19];
  const float* trans2 = (const float*)d_in[20];

  char* ws = (char*)d_ws;
  const size_t SZ_HPUB = (size_t)NL_ * 2 * 4 * 2048 * 8;      //   786,432
  const size_t O_WHP = SZ_HPUB;
  const size_t SZ_WHP = (size_t)NL_ * H_ * G4_ * 2;           // 3,145,728
  const size_t O_WXP = O_WHP + SZ_WHP;
  const size_t SZ_WXP = (size_t)NL_ * DP_ * G4_ * 2;          // 3,932,160
  const size_t O_XF  = O_WXP + SZ_WXP;
  const size_t SZ_XF = 2ull * T_ * 4 * 10 * 64 * 8 * 2;       // 41,943,040
  const size_t O_HO  = O_XF + SZ_XF;
  const size_t SZ_HO = (size_t)NL_ * B_ * T_ * H_ * 2;        // 100,663,296
  const size_t O_LGT = O_HO + SZ_HO;
  const size_t SZ_LGT = 2ull * B_ * T_ * 16 * 4;              //   8,388,608
  const size_t O_W1T = O_LGT + SZ_LGT;
  const size_t O_W2T = O_W1T + 65536;

  unsigned long long* hpub = (unsigned long long*)(ws + 0);
  unsigned short* whp = (unsigned short*)(ws + O_WHP);
  unsigned short* wxp = (unsigned short*)(ws + O_WXP);
  unsigned short* xf  = (unsigned short*)(ws + O_XF);
  unsigned short* ho  = (unsigned short*)(ws + O_HO);
  float* lgt = (float*)(ws + O_LGT);
  float* w1t = (float*)(ws + O_W1T);
  float* w2t = (float*)(ws + O_W2T);

  // invalidate all tags (0xFFFF != any t in [0,512)) — graph-replay safety
  hipMemsetAsync(hpub, 0xFF, SZ_HPUB, stream);
  k_prep_x<<<10240, 256, 0, stream>>>(x, len, xf);
  k_prep_w<<<1856, 256, 0, stream>>>(wp, whp, wxp, W1, W2, w1t, w2t);
  k_rec<<<96, 256, 0, stream>>>(whp, wxp, xf, wp, len, hpub, ho);
  k_logits<<<8192, 256, 0, stream>>>(ho, w1t, w2t, b1, b2, lgt);
  k_crf<<<32, 256, 0, stream>>>(lgt, labels, len, trans1, trans2, (float*)d_out);
}